// Round 1
// baseline (18.041 us; speedup 1.0000x reference)
//
#include <hip/hip_runtime.h>

#define NH 10  // hidden width

// Exact-enough floored mod: matches numpy/jax float32 mod(x+pi, 2pi) semantics.
// q = floor(t * inv2pi) can be off by +-1 near period boundaries; the fma
// remainder is exact (result always representable: < 2^3 magnitude, LSB >= 2^-21),
// and the two conditional corrections restore the true floored-mod value.
__device__ __forceinline__ float wrap_to_pi(float x) {
    const float PI_F      = 3.14159265358979323846f;
    const float TWO_PI_F  = 6.28318530717958647692f;
    const float INV_2PI_F = 0.15915494309189533577f;
    float t = x + PI_F;
    float q = floorf(t * INV_2PI_F);
    float r = fmaf(q, -TWO_PI_F, t);
    r = (r < 0.0f)      ? (r + TWO_PI_F) : r;
    r = (r >= TWO_PI_F) ? (r - TWO_PI_F) : r;
    return r - PI_F;
}

// out(x) = b2 + sum_j w2[j] * tanh(xw * w1[j] + b1[j])
//        = (b2 + sum_j w2[j]) + sum_j (-2*w2[j]) * rcp(exp(2*(xw*w1[j]+b1[j])) + 1)
__global__ __launch_bounds__(256) void nn_pointwise_v4(
    const float* __restrict__ x,
    const float* __restrict__ w1,   // [10,1]
    const float* __restrict__ b1,   // [10]
    const float* __restrict__ w2,   // [1,10]
    const float* __restrict__ b2,   // [1]
    float* __restrict__ out,
    int n4)                          // number of float4 elements
{
    // Per-thread weight prep (uniform addresses -> scalar loads, L2-cached).
    float c1[NH], c0[NH], cw[NH];
    float base = b2[0];
#pragma unroll
    for (int j = 0; j < NH; ++j) {
        float w1j = w1[j];
        float b1j = b1[j];
        float w2j = w2[j];
        c1[j] = 2.0f * w1j;
        c0[j] = 2.0f * b1j;
        cw[j] = -2.0f * w2j;
        base += w2j;
    }

    const float4* __restrict__ xv = (const float4*)x;
    float4*       __restrict__ ov = (float4*)out;

    int idx    = blockIdx.x * blockDim.x + threadIdx.x;
    int stride = gridDim.x * blockDim.x;

    for (int i = idx; i < n4; i += stride) {
        float4 v = xv[i];
        float in[4] = {v.x, v.y, v.z, v.w};
        float o[4];
#pragma unroll
        for (int e = 0; e < 4; ++e) {
            float xw  = wrap_to_pi(in[e]);
            float acc = base;
#pragma unroll
            for (int j = 0; j < NH; ++j) {
                float z2 = fmaf(xw, c1[j], c0[j]);          // 2z
                float ez = __expf(z2);                       // v_exp_f32 fast path
                float rc = __builtin_amdgcn_rcpf(ez + 1.0f); // ~1 ulp rcp
                acc = fmaf(cw[j], rc, acc);
            }
            o[e] = acc;
        }
        ov[i] = make_float4(o[0], o[1], o[2], o[3]);
    }
}

// Scalar tail (n not divisible by 4) — same math.
__global__ __launch_bounds__(256) void nn_pointwise_tail(
    const float* __restrict__ x,
    const float* __restrict__ w1,
    const float* __restrict__ b1,
    const float* __restrict__ w2,
    const float* __restrict__ b2,
    float* __restrict__ out,
    int n_start, int n)
{
    int i = n_start + blockIdx.x * blockDim.x + threadIdx.x;
    if (i >= n) return;
    float base = b2[0];
    float xw = wrap_to_pi(x[i]);
    float acc = 0.0f;
#pragma unroll
    for (int j = 0; j < NH; ++j) {
        float z2 = fmaf(xw, 2.0f * w1[j], 2.0f * b1[j]);
        float ez = __expf(z2);
        float rc = __builtin_amdgcn_rcpf(ez + 1.0f);
        acc = fmaf(-2.0f * w2[j], rc, acc);
        base += w2[j];
    }
    out[i] = base + acc;
}

extern "C" void kernel_launch(void* const* d_in, const int* in_sizes, int n_in,
                              void* d_out, int out_size, void* d_ws, size_t ws_size,
                              hipStream_t stream) {
    const float* x  = (const float*)d_in[0];
    const float* w1 = (const float*)d_in[1];
    const float* b1 = (const float*)d_in[2];
    const float* w2 = (const float*)d_in[3];
    const float* b2 = (const float*)d_in[4];
    float* out = (float*)d_out;

    int n  = in_sizes[0];   // 4194304
    int n4 = n / 4;

    if (n4 > 0) {
        const int threads = 256;
        int blocks = (n4 + threads - 1) / threads;   // 4096 for N=4.19M
        if (blocks > 8192) blocks = 8192;            // grid-stride beyond this
        nn_pointwise_v4<<<blocks, threads, 0, stream>>>(x, w1, b1, w2, b2, out, n4);
    }
    int rem = n - n4 * 4;
    if (rem > 0) {
        nn_pointwise_tail<<<1, 256, 0, stream>>>(x, w1, b1, w2, b2, out, n4 * 4, n);
    }
}

// Round 2
// 17.317 us; speedup vs baseline: 1.0418x; 1.0418x over previous
//
#include <hip/hip_runtime.h>

#define NH 10      // hidden width
#define TPB 256
#define UNROLL 4   // float4s per thread per grid-stride step

// Exact-enough floored mod matching numpy/jax float32 mod(x+pi, 2pi) semantics.
__device__ __forceinline__ float wrap_to_pi(float x) {
    const float PI_F      = 3.14159265358979323846f;
    const float TWO_PI_F  = 6.28318530717958647692f;
    const float INV_2PI_F = 0.15915494309189533577f;
    float t = x + PI_F;
    float q = floorf(t * INV_2PI_F);
    float r = fmaf(q, -TWO_PI_F, t);     // exactly-rounded remainder
    r = (r < 0.0f)      ? (r + TWO_PI_F) : r;
    r = (r >= TWO_PI_F) ? (r - TWO_PI_F) : r;
    return r - PI_F;
}

// out(x) = base + sum_j cw[j] * rcp(exp2(xw*c1[j] + c0[j]) + 1)
// where c1 = 2*w1*log2e, c0 = 2*b1*log2e, cw = -2*w2, base = b2 + sum w2.
struct Consts { float c1[NH], c0[NH], cw[NH], base; };

__device__ __forceinline__ float eval_elem(float xin, const Consts& K) {
    float xw  = wrap_to_pi(xin);
    float acc = K.base;
#pragma unroll
    for (int j = 0; j < NH; ++j) {
        float ez = __builtin_amdgcn_exp2f(fmaf(xw, K.c1[j], K.c0[j]));
        float rc = __builtin_amdgcn_rcpf(ez + 1.0f);
        acc = fmaf(K.cw[j], rc, acc);
    }
    return acc;
}

__device__ __forceinline__ float4 eval4(float4 v, const Consts& K) {
    return make_float4(eval_elem(v.x, K), eval_elem(v.y, K),
                       eval_elem(v.z, K), eval_elem(v.w, K));
}

__global__ __launch_bounds__(TPB) void nn_pointwise_v5(
    const float* __restrict__ x,
    const float* __restrict__ w1,   // [10,1]
    const float* __restrict__ b1,   // [10]
    const float* __restrict__ w2,   // [1,10]
    const float* __restrict__ b2,   // [1]
    float* __restrict__ out,
    int n4)                          // number of float4 elements
{
    const float LOG2E = 1.44269504088896340736f;
    Consts K;
    float base = b2[0];
#pragma unroll
    for (int j = 0; j < NH; ++j) {
        float w1j = w1[j], b1j = b1[j], w2j = w2[j];
        K.c1[j] = 2.0f * LOG2E * w1j;
        K.c0[j] = 2.0f * LOG2E * b1j;
        K.cw[j] = -2.0f * w2j;
        base += w2j;
    }
    K.base = base;

    const float4* __restrict__ xv = (const float4*)x;
    float4*       __restrict__ ov = (float4*)out;

    int tid    = blockIdx.x * TPB + threadIdx.x;
    int stride = gridDim.x * TPB;

    int i = tid;
    // Main path: UNROLL independent float4 loads in flight per step.
    for (; i + (UNROLL - 1) * stride < n4; i += UNROLL * stride) {
        float4 v0 = xv[i];
        float4 v1 = xv[i + stride];
        float4 v2 = xv[i + 2 * stride];
        float4 v3 = xv[i + 3 * stride];
        ov[i]              = eval4(v0, K);
        ov[i + stride]     = eval4(v1, K);
        ov[i + 2 * stride] = eval4(v2, K);
        ov[i + 3 * stride] = eval4(v3, K);
    }
    // Remainder float4s.
    for (; i < n4; i += stride) {
        ov[i] = eval4(xv[i], K);
    }
}

// Scalar tail (n not divisible by 4) — same math, standalone prep.
__global__ __launch_bounds__(TPB) void nn_pointwise_tail(
    const float* __restrict__ x,
    const float* __restrict__ w1,
    const float* __restrict__ b1,
    const float* __restrict__ w2,
    const float* __restrict__ b2,
    float* __restrict__ out,
    int n_start, int n)
{
    int i = n_start + blockIdx.x * TPB + threadIdx.x;
    if (i >= n) return;
    const float LOG2E = 1.44269504088896340736f;
    float base = b2[0];
    float xw = wrap_to_pi(x[i]);
    float acc = 0.0f;
#pragma unroll
    for (int j = 0; j < NH; ++j) {
        float ez = __builtin_amdgcn_exp2f(fmaf(xw, 2.0f * LOG2E * w1[j], 2.0f * LOG2E * b1[j]));
        float rc = __builtin_amdgcn_rcpf(ez + 1.0f);
        acc = fmaf(-2.0f * w2[j], rc, acc);
        base += w2[j];
    }
    out[i] = base + acc;
}

extern "C" void kernel_launch(void* const* d_in, const int* in_sizes, int n_in,
                              void* d_out, int out_size, void* d_ws, size_t ws_size,
                              hipStream_t stream) {
    const float* x  = (const float*)d_in[0];
    const float* w1 = (const float*)d_in[1];
    const float* b1 = (const float*)d_in[2];
    const float* w2 = (const float*)d_in[3];
    const float* b2 = (const float*)d_in[4];
    float* out = (float*)d_out;

    int n  = in_sizes[0];   // 4194304
    int n4 = n / 4;

    if (n4 > 0) {
        // 1024 blocks x 256 threads: each thread handles UNROLL float4s
        // (16 elements) -> weight-prep preamble amortized 4x vs previous round.
        int blocks = (n4 + TPB * UNROLL - 1) / (TPB * UNROLL);  // 1024 for N=4.19M
        if (blocks > 2048) blocks = 2048;
        nn_pointwise_v5<<<blocks, TPB, 0, stream>>>(x, w1, b1, w2, b2, out, n4);
    }
    int rem = n - n4 * 4;
    if (rem > 0) {
        nn_pointwise_tail<<<1, TPB, 0, stream>>>(x, w1, b1, w2, b2, out, n4 * 4, n);
    }
}

// Round 3
// 16.650 us; speedup vs baseline: 1.0836x; 1.0400x over previous
//
#include <hip/hip_runtime.h>

#define NH  10     // hidden width
#define TPB 256
#define TS  4096   // LUT cells over [0, 2pi); nodes 0..TS, padded to TS+4

__constant__ float kPI      = 3.14159265358979323846f;

__device__ __forceinline__ float wrap_r(float x) {
    // r = floored-mod(x + pi, 2pi) in [0, 2pi), matching numpy/jax f32 semantics.
    const float PI_F      = 3.14159265358979323846f;
    const float TWO_PI_F  = 6.28318530717958647692f;
    const float INV_2PI_F = 0.15915494309189533577f;
    float t = x + PI_F;
    float q = floorf(t * INV_2PI_F);
    float r = fmaf(q, -TWO_PI_F, t);     // exactly-rounded remainder
    r = (r < 0.0f)       ? (r + TWO_PI_F) : r;
    r = (r >= TWO_PI_F)  ? (r - TWO_PI_F) : r;
    return r;
}

// Full MLP eval at xw (used only for LUT build + scalar tail).
__device__ __forceinline__ float mlp_eval(float xw,
                                          const float* __restrict__ w1,
                                          const float* __restrict__ b1,
                                          const float* __restrict__ w2,
                                          const float* __restrict__ b2) {
    const float LOG2E = 1.44269504088896340736f;
    float base = b2[0];
    float acc  = 0.0f;
#pragma unroll
    for (int j = 0; j < NH; ++j) {
        float w2j = w2[j];
        float ez = __builtin_amdgcn_exp2f(fmaf(xw, 2.0f * LOG2E * w1[j], 2.0f * LOG2E * b1[j]));
        float rc = __builtin_amdgcn_rcpf(ez + 1.0f);
        acc  = fmaf(-2.0f * w2j, rc, acc);
        base += w2j;
    }
    return base + acc;
}

// Kernel 1: tabulate g[i] = f(i*h - pi) for i in [0, TS+4) into d_ws.
__global__ __launch_bounds__(TPB) void nn_build_lut(
    const float* __restrict__ w1, const float* __restrict__ b1,
    const float* __restrict__ w2, const float* __restrict__ b2,
    float* __restrict__ lutg)
{
    int i = blockIdx.x * TPB + threadIdx.x;
    if (i >= TS + 4) return;
    const float PI_F = 3.14159265358979323846f;
    const float H    = 6.28318530717958647692f / (float)TS;
    float xw = fmaf((float)i, H, -PI_F);
    lutg[i] = mlp_eval(xw, w1, b1, w2, b2);
}

// Kernel 2: stream x -> wrap -> LDS linear interp -> out.
__global__ __launch_bounds__(TPB) void nn_stream_lut(
    const float* __restrict__ x,
    const float* __restrict__ lutg,
    float* __restrict__ out,
    int n4)
{
    __shared__ float lut[TS + 4];
    // Stage table: 16.0 KB via float4 (1025 vec4 loads across 256 threads).
    {
        const float4* __restrict__ lg4 = (const float4*)lutg;
        float4* l4 = (float4*)lut;
        for (int k = threadIdx.x; k < (TS + 4) / 4; k += TPB) l4[k] = lg4[k];
    }
    __syncthreads();

    const float SCALE = (float)TS / 6.28318530717958647692f;  // TS / 2pi
    const float4* __restrict__ xv = (const float4*)x;
    float4*       __restrict__ ov = (float4*)out;

    int tid    = blockIdx.x * TPB + threadIdx.x;
    int stride = gridDim.x * TPB;

    for (int i = tid; i < n4; i += stride) {
        float4 v = xv[i];
        float in[4] = {v.x, v.y, v.z, v.w};
        float o[4];
#pragma unroll
        for (int e = 0; e < 4; ++e) {
            float r  = wrap_r(in[e]);            // [0, 2pi)
            float u  = r * SCALE;                // [0, TS)
            int   idx = (int)u;                  // trunc == floor (u >= 0)
            idx = min(idx, TS - 1);              // u==TS rounding edge
            float frac = u - (float)idx;         // from clamped idx: edge -> 1.0
            float g0 = lut[idx];
            float g1 = lut[idx + 1];             // compiler: ds_read2_b32
            o[e] = fmaf(frac, g1 - g0, g0);
        }
        ov[i] = make_float4(o[0], o[1], o[2], o[3]);
    }
}

// Scalar tail (n not divisible by 4) — exact math, no LUT.
__global__ __launch_bounds__(TPB) void nn_tail(
    const float* __restrict__ x,
    const float* __restrict__ w1, const float* __restrict__ b1,
    const float* __restrict__ w2, const float* __restrict__ b2,
    float* __restrict__ out, int n_start, int n)
{
    int i = n_start + blockIdx.x * TPB + threadIdx.x;
    if (i >= n) return;
    const float PI_F = 3.14159265358979323846f;
    float xw = wrap_r(x[i]) - PI_F;
    out[i] = mlp_eval(xw, w1, b1, w2, b2);
}

extern "C" void kernel_launch(void* const* d_in, const int* in_sizes, int n_in,
                              void* d_out, int out_size, void* d_ws, size_t ws_size,
                              hipStream_t stream) {
    const float* x  = (const float*)d_in[0];
    const float* w1 = (const float*)d_in[1];
    const float* b1 = (const float*)d_in[2];
    const float* w2 = (const float*)d_in[3];
    const float* b2 = (const float*)d_in[4];
    float* out  = (float*)d_out;
    float* lutg = (float*)d_ws;          // (TS+4) floats = 16.4 KB scratch

    int n  = in_sizes[0];                // 4194304
    int n4 = n / 4;

    // Build LUT every call (d_ws is poisoned once; graph replays must be
    // self-contained). 17 blocks, ~2 us.
    nn_build_lut<<<(TS + 4 + TPB - 1) / TPB, TPB, 0, stream>>>(w1, b1, w2, b2, lutg);

    if (n4 > 0) {
        // 2048 blocks x 256 threads -> 8 wg/CU, each thread 2 float4s.
        int blocks = (n4 + TPB - 1) / TPB;
        if (blocks > 2048) blocks = 2048;
        nn_stream_lut<<<blocks, TPB, 0, stream>>>(x, lutg, out, n4);
    }
    int rem = n - n4 * 4;
    if (rem > 0) {
        nn_tail<<<1, TPB, 0, stream>>>(x, w1, b1, w2, b2, out, n4 * 4, n);
    }
}

// Round 4
// 13.198 us; speedup vs baseline: 1.3670x; 1.2615x over previous
//
#include <hip/hip_runtime.h>

#define NH  10     // hidden width
#define TPB 256
#define TS  512    // LUT cells over [0, 2pi); entries 0..TS used, padded to TS+4

// r = floored-mod(x + pi, 2pi) in [0, 2pi), matching numpy/jax f32 semantics.
__device__ __forceinline__ float wrap_r(float x) {
    const float PI_F      = 3.14159265358979323846f;
    const float TWO_PI_F  = 6.28318530717958647692f;
    const float INV_2PI_F = 0.15915494309189533577f;
    float t = x + PI_F;
    float q = floorf(t * INV_2PI_F);
    float r = fmaf(q, -TWO_PI_F, t);     // exactly-rounded remainder
    r = (r < 0.0f)       ? (r + TWO_PI_F) : r;
    r = (r >= TWO_PI_F)  ? (r - TWO_PI_F) : r;
    return r;
}

// Full MLP eval at xw = wrapped angle in (-pi, pi].
__device__ __forceinline__ float mlp_eval(float xw,
                                          const float* __restrict__ w1,
                                          const float* __restrict__ b1,
                                          const float* __restrict__ w2,
                                          const float* __restrict__ b2) {
    const float LOG2E = 1.44269504088896340736f;
    float base = b2[0];
    float acc  = 0.0f;
#pragma unroll
    for (int j = 0; j < NH; ++j) {
        float w2j = w2[j];
        float ez = __builtin_amdgcn_exp2f(fmaf(xw, 2.0f * LOG2E * w1[j], 2.0f * LOG2E * b1[j]));
        float rc = __builtin_amdgcn_rcpf(ez + 1.0f);
        acc  = fmaf(-2.0f * w2j, rc, acc);
        base += w2j;
    }
    return base + acc;
}

// Fused: per-block LDS LUT build (~2 entries/thread, ~1us trans-pipe device-
// wide, hidden under the memory stream) + streaming interp. One dispatch.
__global__ __launch_bounds__(TPB) void nn_fused_lut(
    const float* __restrict__ x,
    const float* __restrict__ w1, const float* __restrict__ b1,
    const float* __restrict__ w2, const float* __restrict__ b2,
    float* __restrict__ out,
    int n4)
{
    __shared__ float lut[TS + 4];

    // Build this block's LUT: entries 0..TS (TS+1 = 513 used, 516 written).
    {
        const float PI_F = 3.14159265358979323846f;
        const float H    = 6.28318530717958647692f / (float)TS;
#pragma unroll
        for (int k = threadIdx.x; k < TS + 4; k += TPB) {
            float xw = fmaf((float)k, H, -PI_F);
            lut[k] = mlp_eval(xw, w1, b1, w2, b2);
        }
    }
    __syncthreads();

    const float SCALE = (float)TS / 6.28318530717958647692f;  // TS / 2pi
    const float4* __restrict__ xv = (const float4*)x;
    float4*       __restrict__ ov = (float4*)out;

    int tid    = blockIdx.x * TPB + threadIdx.x;
    int stride = gridDim.x * TPB;

    for (int i = tid; i < n4; i += stride) {
        float4 v = xv[i];
        float in[4] = {v.x, v.y, v.z, v.w};
        float o[4];
#pragma unroll
        for (int e = 0; e < 4; ++e) {
            float r   = wrap_r(in[e]);           // [0, 2pi)
            float u   = r * SCALE;               // [0, TS)
            int   idx = (int)u;                  // trunc == floor (u >= 0)
            idx = min(idx, TS - 1);              // rounding-edge guard
            float frac = u - (float)idx;
            float g0 = lut[idx];
            float g1 = lut[idx + 1];             // ds_read2_b32 pair
            o[e] = fmaf(frac, g1 - g0, g0);
        }
        ov[i] = make_float4(o[0], o[1], o[2], o[3]);
    }
}

// Scalar tail (n not divisible by 4) — exact math, no LUT.
__global__ __launch_bounds__(TPB) void nn_tail(
    const float* __restrict__ x,
    const float* __restrict__ w1, const float* __restrict__ b1,
    const float* __restrict__ w2, const float* __restrict__ b2,
    float* __restrict__ out, int n_start, int n)
{
    int i = n_start + blockIdx.x * TPB + threadIdx.x;
    if (i >= n) return;
    const float PI_F = 3.14159265358979323846f;
    float xw = wrap_r(x[i]) - PI_F;
    out[i] = mlp_eval(xw, w1, b1, w2, b2);
}

extern "C" void kernel_launch(void* const* d_in, const int* in_sizes, int n_in,
                              void* d_out, int out_size, void* d_ws, size_t ws_size,
                              hipStream_t stream) {
    const float* x  = (const float*)d_in[0];
    const float* w1 = (const float*)d_in[1];
    const float* b1 = (const float*)d_in[2];
    const float* w2 = (const float*)d_in[3];
    const float* b2 = (const float*)d_in[4];
    float* out = (float*)d_out;

    int n  = in_sizes[0];                // 4194304
    int n4 = n / 4;

    if (n4 > 0) {
        // 2048 blocks x 256 threads (8 wg/CU), each thread 2 float4s.
        int blocks = (n4 + TPB - 1) / TPB;
        if (blocks > 2048) blocks = 2048;
        nn_fused_lut<<<blocks, TPB, 0, stream>>>(x, w1, b1, w2, b2, out, n4);
    }
    int rem = n - n4 * 4;
    if (rem > 0) {
        nn_tail<<<1, TPB, 0, stream>>>(x, w1, b1, w2, b2, out, n4 * 4, n);
    }
}